// Round 7
// baseline (140.057 us; speedup 1.0000x reference)
//
#include <hip/hip_runtime.h>

// Problem constants (match reference)
constexpr int B        = 65536;
constexpr int N_SPARSE = 20;
constexpr int N_VARLEN = 3;
constexpr int SEQ_LEN  = 50;
constexpr int VOCAB    = 100000;
constexpr int N_DENSE  = 13;
constexpr int VAR_TOT  = N_VARLEN * SEQ_LEN;   // 150

constexpr int NPAIR = B / 2;                   // 32768 row-pairs
constexpr int NBLK  = NPAIR * 16 / 256;        // 2048 blocks, 16 lanes per pair

typedef int   v4i __attribute__((ext_vector_type(4)));
typedef float v2f __attribute__((ext_vector_type(2)));

// Round-7 structure: force 24-deep gather MLP.
// Evidence: dur pinned at ~59us across fetch 60/84/89 MB and VGPR 28/36 ->
// latency-bound with ~8 outstanding gathers/thread (16 waves x 8 = 128
// in flight -> 0.32 req/cyc -> 57us predicted, 59 measured). This version
// computes all 24 gather offsets (32-bit, saddr form), issues all 24 loads
// in one straight-line cluster, and pins them before a sched_barrier(0) so
// the register allocator must keep all results live -> 384 in flight/CU ->
// ~1 req/cyc TA ceiling -> ~18us gather floor.
__global__ __launch_bounds__(256, 4) void fused_kernel(
    const int*   __restrict__ sparse_ids,     // [B, 20]
    const int*   __restrict__ varlen_ids,     // [B, 3, 50]
    const float* __restrict__ dense_x,        // [B, 13]
    const float* __restrict__ sparse_tables,  // [20, VOCAB]
    const float* __restrict__ varlen_tables,  // [3, VOCAB]
    const float* __restrict__ dense_w,        // [13]
    float*       __restrict__ out)            // [B]
{
    const int tid = blockIdx.x * blockDim.x + threadIdx.x;
    const int g   = tid >> 4;     // row-pair index
    const int t   = tid & 15;     // lane within 16-lane group

    // ---------- id / dense loads — branch-free (clamped/duplicated) --------------
    const v4i* vptr = (const v4i*)(varlen_ids) + (long)g * 75;
    v4i vid[5];
    #pragma unroll
    for (int k = 0; k < 4; ++k) vid[k] = vptr[t + 16 * k];        // chunks 0..63
    const bool v5 = (t < 11);
    {   // chunks 64..74; lanes 11-15 read chunk 64 (already-touched line) and mask
        v4i tmp = vptr[v5 ? (t + 64) : 64];
        const v4i zero4 = {0, 0, 0, 0};
        vid[4] = v5 ? tmp : zero4;
    }

    // sparse ids: lanes 10-15 duplicate lanes 5-9 (same row 2g+1, same chunk) —
    // identical addresses coalesce, no extra lines, no exec-mask branch.
    const int  srow = 2 * g + (t >= 5 ? 1 : 0);
    const int  sch  = t % 5;
    const v4i  sid  = ((const v4i*)sparse_ids)[(long)srow * 5 + sch];

    const float* dx = dense_x + (long)(2 * g) * N_DENSE;          // 26 floats/pair
    const int    td = (t < 13) ? t : 12;                          // clamp, mask via wt
    const float  d0 = dx[td];                                     // row 2g
    const float  d1 = dx[13 + td];                                // row 2g+1
    const float  wt = (t < 13) ? dense_w[td] : 0.f;

    // ---------- compute all 24 gather offsets (32-bit element indices) -----------
    unsigned soff[4];
    {
        const unsigned f0 = 4u * (unsigned)sch;
        #pragma unroll
        for (int j = 0; j < 4; ++j)
            soff[j] = (f0 + j) * (unsigned)VOCAB + (unsigned)sid[j];
    }

    unsigned voff[20];
    unsigned vmask = 0;                       // bit i: varlen id i != 0
    #pragma unroll
    for (int k = 0; k < 5; ++k) {
        const int c = (k < 4) ? (t + 16 * k) : (v5 ? (t + 64) : 64);
        #pragma unroll
        for (int j = 0; j < 4; ++j) {
            const int s = 4 * c + j;                              // pair-position
            const int p = (s >= VAR_TOT) ? (s - VAR_TOT) : s;     // pos within row
            const unsigned v = (p >= 2 * SEQ_LEN) ? 2u : ((p >= SEQ_LEN) ? 1u : 0u);
            voff[4 * k + j] = v * (unsigned)VOCAB + (unsigned)vid[k][j];
            if (vid[k][j] != 0) vmask |= 1u << (4 * k + j);
        }
    }

    // ---------- issue ALL 24 gathers; fence keeps every result live --------------
    float sv[4];
    #pragma unroll
    for (int j = 0; j < 4; ++j) sv[j] = sparse_tables[soff[j]];   // 8 MB table first
    float vv[20];
    #pragma unroll
    for (int i = 0; i < 20; ++i) vv[i] = varlen_tables[voff[i]];
    __builtin_amdgcn_sched_barrier(0);        // no consume above, no gather below

    // ---------- consume ------------------------------------------------------------
    float acc0 = d0 * wt;    // row 2g
    float acc1 = d1 * wt;    // row 2g+1
    #pragma unroll
    for (int k = 0; k < 5; ++k) {
        const int c = (k < 4) ? (t + 16 * k) : (t + 64);
        #pragma unroll
        for (int j = 0; j < 4; ++j) {
            const int  i  = 4 * k + j;
            const int  s  = 4 * c + j;
            const bool r1 = (s >= VAR_TOT);
            // masked lanes (t>=11, k=4) have vmask bit 0 -> add 0 either way
            const float m = ((vmask >> i) & 1u) ? vv[i] : 0.f;
            acc0 += r1 ? 0.f : m;
            acc1 += r1 ? m   : 0.f;
        }
    }
    {
        const float s4 = (sv[0] + sv[1]) + (sv[2] + sv[3]);
        const float ssum = (t < 10) ? s4 : 0.f;   // lanes 10-15 are duplicates
        acc0 += (t < 5)  ? ssum : 0.f;            // lanes 0-4 -> row 2g
        acc1 += (t >= 5) ? ssum : 0.f;            // lanes 5-9 -> row 2g+1
    }

    // ---------- 16-lane butterfly, single float2 store per pair --------------------
    #pragma unroll
    for (int o = 1; o < 16; o <<= 1) {
        acc0 += __shfl_xor(acc0, o);
        acc1 += __shfl_xor(acc1, o);
    }
    if (t == 0) {
        v2f r;
        r[0] = acc0;
        r[1] = acc1;
        __builtin_nontemporal_store(r, (v2f*)(out + 2 * g));
    }
}

extern "C" void kernel_launch(void* const* d_in, const int* in_sizes, int n_in,
                              void* d_out, int out_size, void* d_ws, size_t ws_size,
                              hipStream_t stream) {
    const int*   sparse_ids    = (const int*)d_in[0];
    const int*   varlen_ids    = (const int*)d_in[1];
    const float* dense_x       = (const float*)d_in[2];
    const float* sparse_tables = (const float*)d_in[3];
    const float* varlen_tables = (const float*)d_in[4];
    const float* dense_w       = (const float*)d_in[5];
    float*       out           = (float*)d_out;

    fused_kernel<<<NBLK, 256, 0, stream>>>(
        sparse_ids, varlen_ids, dense_x, sparse_tables, varlen_tables, dense_w, out);
}